// Round 13
// baseline (34.563 us; speedup 1.0000x reference)
//
#include <hip/hip_runtime.h>

typedef __bf16 bf16x8 __attribute__((ext_vector_type(8)));
typedef __bf16 bf16x4 __attribute__((ext_vector_type(4)));
typedef float f32x4 __attribute__((ext_vector_type(4)));

#define IN_F 4096
#define OUT_F 4096
#define M 32
#define BN 128          // n-rows per block
#define KC 512          // k-chunk per block
#define KSTEP 64
#define STEPS 8         // KC / KSTEP
#define NSPLIT 8        // IN_F / KC
#define NTILE 32        // OUT_F / BN

// ---- GEMM: 256 blocks = 32 n-tiles x 8 k-splits, 512 thr = 8 waves.
// R13 change: W staged via REGISTERS (global_load_dwordx4 -> ds_write_b128)
// instead of global_load_lds, testing the hypothesis that DMA fills don't
// allocate normally in L2/L3 (R11: only ~50% of the 64 MB stream was L3-hit
// despite fitting in 256 MB; stream is MSHR-latency-bound at 11.9 B/cyc/CU,
// so hit-rate is the only lever). All accesses compiler-visible -> compiler
// emits counted waits from dataflow; no barriers in the K-loop (waves
// desynced, each wave stages/reads only its own rows). Partials in bf16.
__launch_bounds__(512, 1)
__global__ void qlin_gemm(const float* __restrict__ x,
                          const int* __restrict__ qw,
                          const float* __restrict__ scales,
                          __bf16* __restrict__ part) {
    __shared__ int    Wb[3][BN][KSTEP];   // 3 x 32 KB ring
    __shared__ __bf16 Xs[M][KC];          // 32 KB

    const int t    = threadIdx.x;
    const int lane = t & 63;
    const int wv   = t >> 6;      // 0..7
    const int l16  = lane & 15;
    const int g4   = lane >> 4;   // 0..3
    const int xr   = l16 & 7;

    const int nt    = blockIdx.x & (NTILE - 1);   // 0..31
    const int split = blockIdx.x >> 5;            // 0..7
    const int n0    = nt * BN;
    const int k0    = split * KC;

    const int arow = n0 + wv * 16 + l16;
    const f32x4 sc = *reinterpret_cast<const f32x4*>(
        scales + arow * (IN_F / 128) + split * 4);

    f32x4 a0 = {0.f, 0.f, 0.f, 0.f};
    f32x4 a1 = {0.f, 0.f, 0.f, 0.f};

    // reg-staged W: load 4 x int4 (same per-lane swizzled source addresses
    // the DMA used), later ds_write_b128 to the same linear dest bytes.
    int4 wA[4], wB[4];

    auto issueW = [&](int4* set, int s) {
#pragma unroll
        for (int i = 0; i < 4; ++i) {
            const int r    = wv * 16 + i * 4 + g4;
            const int slot = l16 ^ (r & 7);          // involution, bit3 kept
            set[i] = *reinterpret_cast<const int4*>(
                qw + (size_t)(n0 + r) * IN_F + (k0 + s * KSTEP) + slot * 4);
        }
    };
    auto writeW = [&](int buf, const int4* set) {
#pragma unroll
        for (int i = 0; i < 4; ++i) {
            char* dst = reinterpret_cast<char*>(&Wb[buf][wv * 16 + i * 4][0])
                      + lane * 16;                   // dest byte map == DMA's
            *reinterpret_cast<int4*>(dst) = set[i];
        }
    };

    // ---- prologue: X loads, W sets 0/1 issued, convert+swizzled X write ----
    const int xrow = t >> 4;          // 0..31
    const int cb   = t & 15;
    float4 xa[4], xb[4];
#pragma unroll
    for (int i = 0; i < 4; ++i) {
        const int c = cb + i * 16;    // chunk of 8 floats, 0..63
        xa[i] = *reinterpret_cast<const float4*>(x + (size_t)xrow * IN_F + k0 + c * 8);
        xb[i] = *reinterpret_cast<const float4*>(x + (size_t)xrow * IN_F + k0 + c * 8 + 4);
    }
    issueW(wA, 0);
    issueW(wB, 1);
#pragma unroll
    for (int i = 0; i < 4; ++i) {
        const int c = cb + i * 16;
        bf16x8 v;
        v[0] = (__bf16)xa[i].x; v[1] = (__bf16)xa[i].y;
        v[2] = (__bf16)xa[i].z; v[3] = (__bf16)xa[i].w;
        v[4] = (__bf16)xb[i].x; v[5] = (__bf16)xb[i].y;
        v[6] = (__bf16)xb[i].z; v[7] = (__bf16)xb[i].w;
        const int cs = (c & ~7) | ((c & 7) ^ (xrow & 7));
        *reinterpret_cast<bf16x8*>(&Xs[xrow][cs * 8]) = v;
    }
    asm volatile("" :: "v"(sc[0]), "v"(sc[1]), "v"(sc[2]), "v"(sc[3]));
    __syncthreads();            // X read-only from here; waves desync after

    // fill LDS steps 0,1; keep 2 load-sets in flight
    writeW(0, wA);  issueW(wA, 2);
    writeW(1, wB);  issueW(wB, 3);

    auto compute = [&](int buf, int s) {
#pragma unroll
        for (int q = 0; q < 2; ++q) {
            const int s0 = q * 8 + g4 * 2;
            const int4 w0 = *reinterpret_cast<const int4*>(
                &Wb[buf][wv * 16 + l16][((s0)     ^ xr) * 4]);
            const int4 w1 = *reinterpret_cast<const int4*>(
                &Wb[buf][wv * 16 + l16][((s0 + 1) ^ xr) * 4]);
            const float fs = sc[(2 * s + q) >> 2];   // static after unroll
            bf16x8 af;
            af[0] = (__bf16)((float)w0.x * fs);
            af[1] = (__bf16)((float)w0.y * fs);
            af[2] = (__bf16)((float)w0.z * fs);
            af[3] = (__bf16)((float)w0.w * fs);
            af[4] = (__bf16)((float)w1.x * fs);
            af[5] = (__bf16)((float)w1.y * fs);
            af[6] = (__bf16)((float)w1.z * fs);
            af[7] = (__bf16)((float)w1.w * fs);
            const int xc = (s * 8) | ((q * 4 + g4) ^ xr);
            const bf16x8 b0 = *reinterpret_cast<const bf16x8*>(&Xs[l16][xc * 8]);
            const bf16x8 b1 = *reinterpret_cast<const bf16x8*>(&Xs[16 + l16][xc * 8]);
            a0 = __builtin_amdgcn_mfma_f32_16x16x32_bf16(af, b0, a0, 0, 0, 0);
            a1 = __builtin_amdgcn_mfma_f32_16x16x32_bf16(af, b1, a1, 0, 0, 0);
        }
    };

    // ---- barrier-free main loop: compute(s) from buf s%3, then write step
    // s+2 from the older reg set and reload it with step s+4 ----
#pragma unroll
    for (int s = 0; s < STEPS; ++s) {
        compute(s % 3, s);
        if (s <= 5) {
            int4* set = (s & 1) ? wB : wA;    // parity-static (rule #20)
            writeW((s + 2) % 3, set);
            if (s <= 3) issueW(set, s + 4);
        }
    }

    // ---- bf16 partial write (verified D layout) ----
    __bf16* dst = part + (size_t)split * (M * OUT_F);
    const int nb = n0 + wv * 16 + g4 * 4;
    bf16x4 p0, p1;
#pragma unroll
    for (int j = 0; j < 4; ++j) { p0[j] = (__bf16)a0[j]; p1[j] = (__bf16)a1[j]; }
    *reinterpret_cast<bf16x4*>(dst + (size_t)l16 * OUT_F + nb)        = p0;
    *reinterpret_cast<bf16x4*>(dst + (size_t)(16 + l16) * OUT_F + nb) = p1;
}

// ---- bf16 partials + bias -> fp32 out ----
__global__ __launch_bounds__(256) void qlin_reduce(const __bf16* __restrict__ part,
                                                   const float* __restrict__ bias,
                                                   float* __restrict__ out) {
    const int i = (blockIdx.x * 256 + threadIdx.x) * 4;
    const int n = i & (OUT_F - 1);
    const int m = i >> 12;
    f32x4 s = *reinterpret_cast<const f32x4*>(bias + n);
#pragma unroll
    for (int p = 0; p < NSPLIT; ++p) {
        const bf16x4 u = *reinterpret_cast<const bf16x4*>(
            part + ((size_t)p * M + m) * OUT_F + n);
#pragma unroll
        for (int j = 0; j < 4; ++j) s[j] += (float)u[j];
    }
    *reinterpret_cast<f32x4*>(out + i) = s;
}

// ---- fallback (round-3 validated, no ws needed) ----
__launch_bounds__(512, 2)
__global__ void qlin_fallback(const float* __restrict__ x,
                              const int* __restrict__ qw,
                              const float* __restrict__ scales,
                              const float* __restrict__ bias,
                              float* __restrict__ out) {
    __shared__ float red[8][2][16][20];
    const int t = threadIdx.x, lane = t & 63, wv = t >> 6;
    const int l16 = lane & 15, g = lane >> 4;
    const int n0 = blockIdx.x * 16, row = n0 + l16, kw0 = wv * 512;
    const int*   wp  = qw + row * IN_F + kw0 + g * 8;
    const float* xp0 = x + l16 * IN_F + kw0 + g * 8;
    const float* xp1 = x + (16 + l16) * IN_F + kw0 + g * 8;
    const int scbase = row * (IN_F / 128) + (kw0 >> 7);
    f32x4 acc0 = {0.f,0.f,0.f,0.f}, acc1 = {0.f,0.f,0.f,0.f};
#pragma unroll
    for (int s = 0; s < 16; ++s) {
        const int off = s * 32;
        const int4 w0 = *reinterpret_cast<const int4*>(wp + off);
        const int4 w1 = *reinterpret_cast<const int4*>(wp + off + 4);
        const float scv = scales[scbase + (s >> 2)];
        const float4 xa0 = *reinterpret_cast<const float4*>(xp0 + off);
        const float4 xa1 = *reinterpret_cast<const float4*>(xp0 + off + 4);
        const float4 xb0 = *reinterpret_cast<const float4*>(xp1 + off);
        const float4 xb1 = *reinterpret_cast<const float4*>(xp1 + off + 4);
        bf16x8 af, b0, b1;
        af[0]=(__bf16)((float)w0.x*scv); af[1]=(__bf16)((float)w0.y*scv);
        af[2]=(__bf16)((float)w0.z*scv); af[3]=(__bf16)((float)w0.w*scv);
        af[4]=(__bf16)((float)w1.x*scv); af[5]=(__bf16)((float)w1.y*scv);
        af[6]=(__bf16)((float)w1.z*scv); af[7]=(__bf16)((float)w1.w*scv);
        b0[0]=(__bf16)xa0.x; b0[1]=(__bf16)xa0.y; b0[2]=(__bf16)xa0.z; b0[3]=(__bf16)xa0.w;
        b0[4]=(__bf16)xa1.x; b0[5]=(__bf16)xa1.y; b0[6]=(__bf16)xa1.z; b0[7]=(__bf16)xa1.w;
        b1[0]=(__bf16)xb0.x; b1[1]=(__bf16)xb0.y; b1[2]=(__bf16)xb0.z; b1[3]=(__bf16)xb0.w;
        b1[4]=(__bf16)xb1.x; b1[5]=(__bf16)xb1.y; b1[6]=(__bf16)xb1.z; b1[7]=(__bf16)xb1.w;
        acc0 = __builtin_amdgcn_mfma_f32_16x16x32_bf16(af, b0, acc0, 0,0,0);
        acc1 = __builtin_amdgcn_mfma_f32_16x16x32_bf16(af, b1, acc1, 0,0,0);
    }
    *reinterpret_cast<f32x4*>(&red[wv][0][l16][g*4]) = acc0;
    *reinterpret_cast<f32x4*>(&red[wv][1][l16][g*4]) = acc1;
    __syncthreads();
    const int h = t >> 8, ml = (t >> 4) & 15, nl = t & 15;
    float sum = bias[n0 + nl];
#pragma unroll
    for (int w = 0; w < 8; ++w) sum += red[w][h & 1][ml][nl];
    if (t < 512) out[(h * 16 + ml) * OUT_F + n0 + nl] = sum;
}

extern "C" void kernel_launch(void* const* d_in, const int* in_sizes, int n_in,
                              void* d_out, int out_size, void* d_ws, size_t ws_size,
                              hipStream_t stream) {
    const float* x      = (const float*)d_in[0];
    const int*   qw     = (const int*)d_in[1];
    const float* scales = (const float*)d_in[2];
    const float* bias   = (const float*)d_in[3];
    float* out = (float*)d_out;

    const size_t NEED = (size_t)NSPLIT * M * OUT_F * sizeof(__bf16);   // 2 MB
    if (ws_size >= NEED) {
        __bf16* part = (__bf16*)d_ws;
        qlin_gemm<<<dim3(NTILE * NSPLIT), dim3(512), 0, stream>>>(x, qw, scales, part);
        qlin_reduce<<<dim3((M * OUT_F) / (256 * 4)), dim3(256), 0, stream>>>(part, bias, out);
    } else {
        qlin_fallback<<<dim3(OUT_F / 16), dim3(512), 0, stream>>>(
            x, qw, scales, bias, out);
    }
}

// Round 14
// 19.734 us; speedup vs baseline: 1.7514x; 1.7514x over previous
//
#include <hip/hip_runtime.h>

typedef __bf16 bf16x8 __attribute__((ext_vector_type(8)));
typedef __bf16 bf16x4 __attribute__((ext_vector_type(4)));
typedef float f32x4 __attribute__((ext_vector_type(4)));

#define IN_F 4096
#define OUT_F 4096
#define M 32
#define BN 128          // n-rows per block
#define KC 512          // k-chunk per block
#define KSTEP 64
#define STEPS 8         // KC / KSTEP
#define NSPLIT 8        // IN_F / KC
#define NTILE 32        // OUT_F / BN

// async global->LDS, 16B/lane, LDS dest = wave-uniform base + lane*16
__device__ __forceinline__ void gload16(const void* g, void* l) {
    __builtin_amdgcn_global_load_lds(
        (const __attribute__((address_space(1))) void*)g,
        (__attribute__((address_space(3))) void*)l, 16, 0, 0);
}

template <int N>
__device__ __forceinline__ void wait_vmcnt() {
    asm volatile("s_waitcnt vmcnt(%0)" :: "n"(N) : "memory");
}

// ---- GEMM: 256 blocks = 32 n-tiles x 8 k-splits, 512 thr = 8 waves.
// R12 structure (best known, 19.85us): LDS 128 KB, 1 block/CU; W via
// global_load_lds (R13 proved reg-staging is 75% slower), depth-3 ring,
// barrier-free K-loop with per-wave counted vmcnt 8/4/0, XOR-preswizzled
// source + matching XOR ds_read. R14: partials in bf16 (numerics validated
// in R13: absmax stays 0.125) -> halves partial traffic + reduce node.
__launch_bounds__(512, 2)
__global__ void qlin_gemm(const float* __restrict__ x,
                          const int* __restrict__ qw,
                          const float* __restrict__ scales,
                          __bf16* __restrict__ part) {
    __shared__ int    Wb[3][BN][KSTEP];   // 3 x 32 KB ring
    __shared__ __bf16 Xs[M][KC];          // 32 KB

    const int t    = threadIdx.x;
    const int lane = t & 63;
    const int wv   = t >> 6;      // 0..7
    const int l16  = lane & 15;
    const int g4   = lane >> 4;   // 0..3
    const int xr   = l16 & 7;

    const int nt    = blockIdx.x & (NTILE - 1);   // 0..31
    const int split = blockIdx.x >> 5;            // 0..7
    const int n0    = nt * BN;
    const int k0    = split * KC;

    // wave's A-row scales: 4 groups of this split; loaded+pinned before the
    // barrier so the K-loop's vmcnt counts only W stages.
    const int arow = n0 + wv * 16 + l16;
    const f32x4 sc = *reinterpret_cast<const f32x4*>(
        scales + arow * (IN_F / 128) + split * 4);

    f32x4 a0 = {0.f, 0.f, 0.f, 0.f};
    f32x4 a1 = {0.f, 0.f, 0.f, 0.f};

    auto stageW = [&](int buf, int s) {
        const int kk = k0 + s * KSTEP;
#pragma unroll
        for (int i = 0; i < 4; ++i) {
            const int r    = wv * 16 + i * 4 + g4;   // LDS row == tile row
            const int slot = l16 ^ (r & 7);          // involution, bit3 kept
            gload16(qw + (size_t)(n0 + r) * IN_F + kk + slot * 4,
                    &Wb[buf][wv * 16 + i * 4][0]);
        }
    };

    // ---- prologue: X loads first, W stages 0/1 next (all prologue traffic
    // in flight together), then convert+swizzled ds_write, one barrier ----
    const int xrow = t >> 4;          // 0..31
    const int cb   = t & 15;
    float4 xa[4], xb[4];
#pragma unroll
    for (int i = 0; i < 4; ++i) {
        const int c = cb + i * 16;    // chunk of 8 floats, 0..63
        xa[i] = *reinterpret_cast<const float4*>(x + (size_t)xrow * IN_F + k0 + c * 8);
        xb[i] = *reinterpret_cast<const float4*>(x + (size_t)xrow * IN_F + k0 + c * 8 + 4);
    }
    stageW(0, 0);
    stageW(1, 1);
#pragma unroll
    for (int i = 0; i < 4; ++i) {
        const int c = cb + i * 16;
        bf16x8 v;
        v[0] = (__bf16)xa[i].x; v[1] = (__bf16)xa[i].y;
        v[2] = (__bf16)xa[i].z; v[3] = (__bf16)xa[i].w;
        v[4] = (__bf16)xb[i].x; v[5] = (__bf16)xb[i].y;
        v[6] = (__bf16)xb[i].z; v[7] = (__bf16)xb[i].w;
        const int cs = (c & ~7) | ((c & 7) ^ (xrow & 7));
        *reinterpret_cast<bf16x8*>(&Xs[xrow][cs * 8]) = v;
    }
    asm volatile("" :: "v"(sc[0]), "v"(sc[1]), "v"(sc[2]), "v"(sc[3]));
    __syncthreads();            // drains everything; X read-only from here

    auto compute = [&](int buf, int s) {
#pragma unroll
        for (int q = 0; q < 2; ++q) {
            const int s0 = q * 8 + g4 * 2;
            const int4 w0 = *reinterpret_cast<const int4*>(
                &Wb[buf][wv * 16 + l16][((s0)     ^ xr) * 4]);
            const int4 w1 = *reinterpret_cast<const int4*>(
                &Wb[buf][wv * 16 + l16][((s0 + 1) ^ xr) * 4]);
            const float fs = sc[(2 * s + q) >> 2];   // static after unroll
            bf16x8 af;
            af[0] = (__bf16)((float)w0.x * fs);
            af[1] = (__bf16)((float)w0.y * fs);
            af[2] = (__bf16)((float)w0.z * fs);
            af[3] = (__bf16)((float)w0.w * fs);
            af[4] = (__bf16)((float)w1.x * fs);
            af[5] = (__bf16)((float)w1.y * fs);
            af[6] = (__bf16)((float)w1.z * fs);
            af[7] = (__bf16)((float)w1.w * fs);
            const int xc = (s * 8) | ((q * 4 + g4) ^ xr);
            const bf16x8 b0 = *reinterpret_cast<const bf16x8*>(&Xs[l16][xc * 8]);
            const bf16x8 b1 = *reinterpret_cast<const bf16x8*>(&Xs[16 + l16][xc * 8]);
            a0 = __builtin_amdgcn_mfma_f32_16x16x32_bf16(af, b0, a0, 0, 0, 0);
            a1 = __builtin_amdgcn_mfma_f32_16x16x32_bf16(af, b1, a1, 0, 0, 0);
        }
    };

    // ---- barrier-free main loop (depth-3 ring, counted vmcnt 8/4/0) ----
#pragma unroll
    for (int s = 0; s < STEPS; ++s) {
        // ds_reads of buf (s-1)%3 retired before stage(s+2) overwrites it
        asm volatile("s_waitcnt lgkmcnt(0)" ::: "memory");
        if (s + 2 < STEPS) stageW((s + 2) % 3, s + 2);
        if (s < STEPS - 2)       wait_vmcnt<8>();
        else if (s == STEPS - 2) wait_vmcnt<4>();
        else                     wait_vmcnt<0>();
        compute(s % 3, s);
    }

    // ---- bf16 partial write (verified D layout; numerics proven in R13) ----
    __bf16* dst = part + (size_t)split * (M * OUT_F);
    const int nb = n0 + wv * 16 + g4 * 4;
    bf16x4 p0, p1;
#pragma unroll
    for (int j = 0; j < 4; ++j) { p0[j] = (__bf16)a0[j]; p1[j] = (__bf16)a1[j]; }
    *reinterpret_cast<bf16x4*>(dst + (size_t)l16 * OUT_F + nb)        = p0;
    *reinterpret_cast<bf16x4*>(dst + (size_t)(16 + l16) * OUT_F + nb) = p1;
}

// ---- bf16 partials + bias -> fp32 out ----
__global__ __launch_bounds__(256) void qlin_reduce(const __bf16* __restrict__ part,
                                                   const float* __restrict__ bias,
                                                   float* __restrict__ out) {
    const int i = (blockIdx.x * 256 + threadIdx.x) * 4;
    const int n = i & (OUT_F - 1);
    const int m = i >> 12;
    f32x4 s = *reinterpret_cast<const f32x4*>(bias + n);
#pragma unroll
    for (int p = 0; p < NSPLIT; ++p) {
        const bf16x4 u = *reinterpret_cast<const bf16x4*>(
            part + ((size_t)p * M + m) * OUT_F + n);
#pragma unroll
        for (int j = 0; j < 4; ++j) s[j] += (float)u[j];
    }
    *reinterpret_cast<f32x4*>(out + i) = s;
}

// ---- fallback (round-3 validated, no ws needed) ----
__launch_bounds__(512, 2)
__global__ void qlin_fallback(const float* __restrict__ x,
                              const int* __restrict__ qw,
                              const float* __restrict__ scales,
                              const float* __restrict__ bias,
                              float* __restrict__ out) {
    __shared__ float red[8][2][16][20];
    const int t = threadIdx.x, lane = t & 63, wv = t >> 6;
    const int l16 = lane & 15, g = lane >> 4;
    const int n0 = blockIdx.x * 16, row = n0 + l16, kw0 = wv * 512;
    const int*   wp  = qw + row * IN_F + kw0 + g * 8;
    const float* xp0 = x + l16 * IN_F + kw0 + g * 8;
    const float* xp1 = x + (16 + l16) * IN_F + kw0 + g * 8;
    const int scbase = row * (IN_F / 128) + (kw0 >> 7);
    f32x4 acc0 = {0.f,0.f,0.f,0.f}, acc1 = {0.f,0.f,0.f,0.f};
#pragma unroll
    for (int s = 0; s < 16; ++s) {
        const int off = s * 32;
        const int4 w0 = *reinterpret_cast<const int4*>(wp + off);
        const int4 w1 = *reinterpret_cast<const int4*>(wp + off + 4);
        const float scv = scales[scbase + (s >> 2)];
        const float4 xa0 = *reinterpret_cast<const float4*>(xp0 + off);
        const float4 xa1 = *reinterpret_cast<const float4*>(xp0 + off + 4);
        const float4 xb0 = *reinterpret_cast<const float4*>(xp1 + off);
        const float4 xb1 = *reinterpret_cast<const float4*>(xp1 + off + 4);
        bf16x8 af, b0, b1;
        af[0]=(__bf16)((float)w0.x*scv); af[1]=(__bf16)((float)w0.y*scv);
        af[2]=(__bf16)((float)w0.z*scv); af[3]=(__bf16)((float)w0.w*scv);
        af[4]=(__bf16)((float)w1.x*scv); af[5]=(__bf16)((float)w1.y*scv);
        af[6]=(__bf16)((float)w1.z*scv); af[7]=(__bf16)((float)w1.w*scv);
        b0[0]=(__bf16)xa0.x; b0[1]=(__bf16)xa0.y; b0[2]=(__bf16)xa0.z; b0[3]=(__bf16)xa0.w;
        b0[4]=(__bf16)xa1.x; b0[5]=(__bf16)xa1.y; b0[6]=(__bf16)xa1.z; b0[7]=(__bf16)xa1.w;
        b1[0]=(__bf16)xb0.x; b1[1]=(__bf16)xb0.y; b1[2]=(__bf16)xb0.z; b1[3]=(__bf16)xb0.w;
        b1[4]=(__bf16)xb1.x; b1[5]=(__bf16)xb1.y; b1[6]=(__bf16)xb1.z; b1[7]=(__bf16)xb1.w;
        acc0 = __builtin_amdgcn_mfma_f32_16x16x32_bf16(af, b0, acc0, 0,0,0);
        acc1 = __builtin_amdgcn_mfma_f32_16x16x32_bf16(af, b1, acc1, 0,0,0);
    }
    *reinterpret_cast<f32x4*>(&red[wv][0][l16][g*4]) = acc0;
    *reinterpret_cast<f32x4*>(&red[wv][1][l16][g*4]) = acc1;
    __syncthreads();
    const int h = t >> 8, ml = (t >> 4) & 15, nl = t & 15;
    float sum = bias[n0 + nl];
#pragma unroll
    for (int w = 0; w < 8; ++w) sum += red[w][h & 1][ml][nl];
    if (t < 512) out[(h * 16 + ml) * OUT_F + n0 + nl] = sum;
}

extern "C" void kernel_launch(void* const* d_in, const int* in_sizes, int n_in,
                              void* d_out, int out_size, void* d_ws, size_t ws_size,
                              hipStream_t stream) {
    const float* x      = (const float*)d_in[0];
    const int*   qw     = (const int*)d_in[1];
    const float* scales = (const float*)d_in[2];
    const float* bias   = (const float*)d_in[3];
    float* out = (float*)d_out;

    const size_t NEED = (size_t)NSPLIT * M * OUT_F * sizeof(__bf16);   // 2 MB
    if (ws_size >= NEED) {
        __bf16* part = (__bf16*)d_ws;
        qlin_gemm<<<dim3(NTILE * NSPLIT), dim3(512), 0, stream>>>(x, qw, scales, part);
        qlin_reduce<<<dim3((M * OUT_F) / (256 * 4)), dim3(256), 0, stream>>>(part, bias, out);
    } else {
        qlin_fallback<<<dim3(OUT_F / 16), dim3(512), 0, stream>>>(
            x, qw, scales, bias, out);
    }
}